// Round 3
// baseline (273.726 us; speedup 1.0000x reference)
//
#include <hip/hip_runtime.h>
#include <hip/hip_bf16.h>

#define DMODEL 1024
#define SEQ    2048
#define NB     2
#define NH     16
#define DKH    64

typedef __attribute__((ext_vector_type(4))) float  f32x4;
typedef __attribute__((ext_vector_type(8))) __bf16 bf16x8;
typedef __attribute__((ext_vector_type(8))) short  short8;
typedef __attribute__((ext_vector_type(4))) short  short4v;

__device__ __forceinline__ short f2bf(float f) {
    __bf16 b = (__bf16)f;
    return __builtin_bit_cast(short, b);
}

__device__ __forceinline__ f32x4 mfma16(short8 a, short8 b, f32x4 c) {
    return __builtin_amdgcn_mfma_f32_16x16x32_bf16(
        __builtin_bit_cast(bf16x8, a), __builtin_bit_cast(bf16x8, b), c, 0, 0, 0);
}

// async global->LDS, 16B per lane (dest = wave-uniform base + lane*16)
__device__ __forceinline__ void async16(const void* gptr, void* lptr) {
    __builtin_amdgcn_global_load_lds(
        (const __attribute__((address_space(1))) void*)gptr,
        (__attribute__((address_space(3))) void*)lptr, 16, 0, 0);
}

// ---------------------------------------------------------------------------
// Prep (fused): bid<12288 -> Q/K/V fp32->bf16; else -> W transpose+cast.
// ---------------------------------------------------------------------------
__global__ __launch_bounds__(256) void prep_kernel(
    const float* __restrict__ Q, const float* __restrict__ K,
    const float* __restrict__ V,
    const float* __restrict__ W0, const float* __restrict__ W1,
    const float* __restrict__ W2, const float* __restrict__ W3,
    short* __restrict__ xb, short* __restrict__ WT) {
    __shared__ float tile[32][33];
    const int bid = blockIdx.x;
    if (bid < 12288) {
        const int z = bid >> 12;
        const float* src = (z == 0) ? Q : (z == 1) ? K : V;
        size_t i = (size_t)(bid & 4095) * 256 + threadIdx.x;  // float4 idx, 1M/input
        float4 v = ((const float4*)src)[i];
        short4v s;
        s[0] = f2bf(v.x); s[1] = f2bf(v.y); s[2] = f2bf(v.z); s[3] = f2bf(v.w);
        ((short4v*)(xb + (size_t)z * (NB * SEQ) * DMODEL))[i] = s;
    } else {
        const int t = bid - 12288;
        const int z = t >> 10, tt = t & 1023;
        const float* W = (z == 0) ? W0 : (z == 1) ? W1 : (z == 2) ? W2 : W3;
        short* o = WT + (size_t)z * DMODEL * DMODEL;
        const int k0 = (tt & 31) * 32, n0 = (tt >> 5) * 32;
        const int c = threadIdx.x & 31, r8 = threadIdx.x >> 5;
#pragma unroll
        for (int rr = 0; rr < 4; ++rr) {
            int row = r8 + 8 * rr;
            tile[row][c] = W[(size_t)(k0 + row) * DMODEL + n0 + c];
        }
        __syncthreads();
#pragma unroll
        for (int rr = 0; rr < 4; ++rr) {
            int n = r8 + 8 * rr;
            o[(size_t)(n0 + n) * DMODEL + k0 + c] = f2bf(tile[c][n]);
        }
    }
}

// ---------------------------------------------------------------------------
// m97-style NT GEMM core: 128x128 tile, BK=64, global_load_lds(16B) staging,
// 4 waves (2x2), each wave 64x64 out = 4x4 fragments of 16x16x32.
// ---------------------------------------------------------------------------
__device__ __forceinline__ void gemm128_core(
    const short* __restrict__ A, const short* __restrict__ BT,
    int i0, int n0, short (*A_lds)[64], short (*B_lds)[64], f32x4 acc[4][4]) {
    const int tid = threadIdx.x, lane = tid & 63, w = tid >> 6;
    const int wrow = w >> 1, wcol = w & 1, g = lane >> 4, qi = lane & 15;
    const int srow = lane >> 3, scol = (lane & 7) * 8;  // staging: lane covers 16B

    for (int k0 = 0; k0 < DMODEL; k0 += 64) {
#pragma unroll
        for (int i = 0; i < 4; ++i) {
            int t = w * 4 + i;  // 1KB chunk = 8 rows of 64 bf16
            async16(A  + (size_t)(i0 + 8 * t + srow) * DMODEL + k0 + scol, &A_lds[8 * t][0]);
            async16(BT + (size_t)(n0 + 8 * t + srow) * DMODEL + k0 + scol, &B_lds[8 * t][0]);
        }
        __syncthreads();
#pragma unroll
        for (int kc = 0; kc < 2; ++kc) {
            short8 a[4], b[4];
#pragma unroll
            for (int mt = 0; mt < 4; ++mt)
                a[mt] = *(const short8*)&A_lds[wrow * 64 + mt * 16 + qi][kc * 32 + g * 8];
#pragma unroll
            for (int nt = 0; nt < 4; ++nt)
                b[nt] = *(const short8*)&B_lds[wcol * 64 + nt * 16 + qi][kc * 32 + g * 8];
#pragma unroll
            for (int mt = 0; mt < 4; ++mt)
#pragma unroll
                for (int nt = 0; nt < 4; ++nt)
                    acc[mt][nt] = mfma16(a[mt], b[nt], acc[mt][nt]);
        }
        __syncthreads();
    }
}

// ---------------------------------------------------------------------------
// QKV projection: z=0 q (scaled by log2e/sqrt(dk)), z=1 k -> [B,H,S,Dk];
// z=2 v -> [B,H,Dk,S]
// ---------------------------------------------------------------------------
__global__ __launch_bounds__(256) void qkv_gemm_kernel(
    const short* __restrict__ xb, const short* __restrict__ WT,
    const float* __restrict__ bq, const float* __restrict__ bk,
    const float* __restrict__ bv,
    short* __restrict__ q_out, short* __restrict__ k_out, short* __restrict__ vT_out) {
    __shared__ __align__(16) short lds[128 * 128];
    short (*A_lds)[64]  = (short(*)[64])lds;
    short (*B_lds)[64]  = (short(*)[64])(lds + 128 * 64);
    short (*C_lds)[128] = (short(*)[128])lds;

    const int z = blockIdx.z;
    const short* A  = xb + (size_t)z * (NB * SEQ) * DMODEL;
    const short* BT = WT + (size_t)z * DMODEL * DMODEL;
    const float* bias = (z == 0) ? bq : (z == 1) ? bk : bv;
    // fold 1/sqrt(64) * log2(e) into q so attn softmax runs in exp2 domain
    const float scale = (z == 0) ? 0.125f * 1.44269504f : 1.0f;
    const int i0 = blockIdx.x * 128, n0 = blockIdx.y * 128;
    const int tid = threadIdx.x, lane = tid & 63, w = tid >> 6;
    const int wrow = w >> 1, wcol = w & 1, g = lane >> 4, qi = lane & 15;

    f32x4 acc[4][4];
#pragma unroll
    for (int mt = 0; mt < 4; ++mt)
#pragma unroll
        for (int nt = 0; nt < 4; ++nt) acc[mt][nt] = f32x4{0.f, 0.f, 0.f, 0.f};

    gemm128_core(A, BT, i0, n0, A_lds, B_lds, acc);

    // epilogue: bias+scale -> bf16 -> LDS repack ([i][n] for q/k, [n][i] for v)
#pragma unroll
    for (int mt = 0; mt < 4; ++mt)
#pragma unroll
        for (int nt = 0; nt < 4; ++nt) {
            int nl = wcol * 64 + nt * 16 + qi;
            float bb = bias[n0 + nl];
#pragma unroll
            for (int r = 0; r < 4; ++r) {
                int il = wrow * 64 + mt * 16 + 4 * g + r;
                short v = f2bf((acc[mt][nt][r] + bb) * scale);
                if (z == 2) C_lds[nl][il] = v;
                else        C_lds[il][nl] = v;
            }
        }
    __syncthreads();
    const int b = i0 >> 11, s0 = i0 & 2047;
#pragma unroll
    for (int rr = 0; rr < 8; ++rr) {
        int c = tid + 256 * rr;              // 2048 chunks of 8 shorts
        int row = c >> 4, off = (c & 15) * 8;
        short8 v8 = *(const short8*)&C_lds[row][off];
        if (z == 2) {  // row = n-local (head,d), off over s
            int h = (n0 + row) >> 6, d = (n0 + row) & 63;
            *(short8*)(vT_out + ((size_t)(b * NH + h) * DKH + d) * SEQ + s0 + off) = v8;
        } else {       // row = s-local, off over n (head,d)
            int h = (n0 + off) >> 6, d = (n0 + off) & 63;
            short* outp = (z == 0) ? q_out : k_out;
            *(short8*)(outp + ((size_t)(b * NH + h) * SEQ + (s0 + row)) * DKH + d) = v8;
        }
    }
}

// ---------------------------------------------------------------------------
// Flash attention: grid (S/64, B*H), 4 waves x 16 queries, KVBLK=64.
// Double-buffered K/V, XOR-swizzled LDS (G4), exp2-domain softmax,
// async-stage split (T14), defer-max (T13). Q pre-scaled by log2e/sqrt(Dk).
// LDS = 40960 B -> 4 blocks/CU.
// ---------------------------------------------------------------------------
__global__ __launch_bounds__(256) void attn_kernel(
    const short* __restrict__ q_ws, const short* __restrict__ k_ws,
    const short* __restrict__ vT_ws, short* __restrict__ attn_out) {
    __shared__ __align__(16) short K_lds[2][64][64];
    __shared__ __align__(16) short V_lds[2][64][64];   // vT tile: [d][j]
    __shared__ __align__(16) short P_lds[4][16][64];   // per-wave
    const int bh = blockIdx.y, q0 = blockIdx.x * 64;
    const short* qg = q_ws + (size_t)bh * SEQ * DKH;
    const short* kg = k_ws + (size_t)bh * SEQ * DKH;
    const short* vg = vT_ws + (size_t)bh * DKH * SEQ;
    const int tid = threadIdx.x, lane = tid & 63, w = tid >> 6;
    const int g = lane >> 4, qi = lane & 15;
    const int swz = (qi & 7) << 3;  // XOR on short-index == byte ^ ((row&7)<<4)

    // Q fragments (B operand), rows q0 + w*16 + qi — live whole kernel
    short8 qf[2];
#pragma unroll
    for (int c = 0; c < 2; ++c)
        qf[c] = *(const short8*)(qg + (size_t)(q0 + w * 16 + qi) * DKH + c * 32 + g * 8);

    // staging registers (T14 issue-early / write-late); rowsw = row-XOR for store
    const int srow = tid >> 3;          // rows 0..31 (+32 for rr=1)
    const int soff = (tid & 7) * 8;
    short8 kr[2], vr[2];
    auto LOADT = [&](int it) {
        const short* kbase = kg + (size_t)it * 64 * DKH;
        const short* vbase = vg + it * 64;
#pragma unroll
        for (int rr = 0; rr < 2; ++rr) {
            int row = srow + 32 * rr;
            kr[rr] = *(const short8*)(kbase + (size_t)row * DKH + soff);
            vr[rr] = *(const short8*)(vbase + (size_t)row * SEQ + soff);
        }
    };
    auto STORET = [&](int buf) {
#pragma unroll
        for (int rr = 0; rr < 2; ++rr) {
            int row = srow + 32 * rr;
            int so = soff ^ ((row & 7) << 3);
            *(short8*)&K_lds[buf][row][so] = kr[rr];
            *(short8*)&V_lds[buf][row][so] = vr[rr];
        }
    };

    LOADT(0);
    STORET(0);

    f32x4 o[4];
#pragma unroll
    for (int dt = 0; dt < 4; ++dt) o[dt] = f32x4{0.f, 0.f, 0.f, 0.f};
    float m_run = -1e30f, l_run = 0.f;
    const int NT = SEQ / 64;

    for (int it = 0; it < NT; ++it) {
        const int cur = it & 1;
        __syncthreads();  // buf[cur] staged for all; buf[cur^1] free to overwrite
        if (it + 1 < NT) LOADT(it + 1);  // issue next-tile global loads early

        // S^T = K * Q^T : lane holds 16 scores for query qi, keys jt*16+4*g+r
        f32x4 st[4];
#pragma unroll
        for (int jt = 0; jt < 4; ++jt) st[jt] = f32x4{0.f, 0.f, 0.f, 0.f};
#pragma unroll
        for (int jt = 0; jt < 4; ++jt)
#pragma unroll
            for (int c = 0; c < 2; ++c) {
                short8 a = *(const short8*)&K_lds[cur][jt * 16 + qi][(c * 32 + g * 8) ^ swz];
                st[jt] = mfma16(a, qf[c], st[jt]);
            }

        float sv[16], pmax = -1e30f;
#pragma unroll
        for (int jt = 0; jt < 4; ++jt)
#pragma unroll
            for (int r = 0; r < 4; ++r) {
                float x = st[jt][r];  // already in log2 domain
                sv[jt * 4 + r] = x;
                pmax = fmaxf(pmax, x);
            }
        pmax = fmaxf(pmax, __shfl_xor(pmax, 16));
        pmax = fmaxf(pmax, __shfl_xor(pmax, 32));

        // defer-max (T13): threshold 8*log2e in exp2 domain
        float m_new = m_run, fct = 1.0f;
        const int need = !__all(pmax <= m_run + 11.54f);
        if (need) { m_new = fmaxf(m_run, pmax); fct = exp2f(m_run - m_new); }

        float psum = 0.f;
#pragma unroll
        for (int i = 0; i < 16; ++i) {
            float p = exp2f(sv[i] - m_new);  // bare v_exp_f32
            sv[i] = p;
            psum += p;
        }
        psum += __shfl_xor(psum, 16);
        psum += __shfl_xor(psum, 32);
        l_run = l_run * fct + psum;
        m_run = m_new;

        // P (bf16) to per-wave LDS: row = query qi, col = key (swizzled)
#pragma unroll
        for (int jt = 0; jt < 4; ++jt) {
            short4v pk;
#pragma unroll
            for (int r = 0; r < 4; ++r) pk[r] = f2bf(sv[jt * 4 + r]);
            *(short4v*)&P_lds[w][qi][(jt * 16 + 4 * g) ^ swz] = pk;
        }

        if (need) {  // rescale O rows (query 4*g+r)
            float fr[4];
#pragma unroll
            for (int r = 0; r < 4; ++r) fr[r] = __shfl(fct, 4 * g + r);
#pragma unroll
            for (int dt = 0; dt < 4; ++dt)
#pragma unroll
                for (int r = 0; r < 4; ++r) o[dt][r] *= fr[r];
        }

        if (it + 1 < NT) STORET(cur ^ 1);  // write-late into the free buffer

        // O += P * V  (P per-wave; compiler orders ds_write->ds_read via lgkm)
#pragma unroll
        for (int c = 0; c < 2; ++c) {
            short8 ap = *(const short8*)&P_lds[w][qi][(c * 32 + g * 8) ^ swz];
#pragma unroll
            for (int dt = 0; dt < 4; ++dt) {
                short8 bvv = *(const short8*)&V_lds[cur][dt * 16 + qi][(c * 32 + g * 8) ^ swz];
                o[dt] = mfma16(ap, bvv, o[dt]);
            }
        }
    }

    float linv = 1.f / l_run;
    float lr[4];
#pragma unroll
    for (int r = 0; r < 4; ++r) lr[r] = __shfl(linv, 4 * g + r);
    const int b = bh >> 4, h = bh & 15;
#pragma unroll
    for (int dt = 0; dt < 4; ++dt)
#pragma unroll
        for (int r = 0; r < 4; ++r) {
            int spos = q0 + w * 16 + 4 * g + r;
            attn_out[(size_t)(b * SEQ + spos) * DMODEL + h * 64 + dt * 16 + qi] =
                f2bf(o[dt][r] * lr[r]);
        }
}

// ---------------------------------------------------------------------------
// Output projection: bf16 NT GEMM -> fp32 + bias, direct stores
// ---------------------------------------------------------------------------
__global__ __launch_bounds__(256) void oproj_kernel(
    const short* __restrict__ attn, const short* __restrict__ WoT,
    const float* __restrict__ bo, float* __restrict__ out) {
    __shared__ __align__(16) short lds[128 * 128];
    short (*A_lds)[64] = (short(*)[64])lds;
    short (*B_lds)[64] = (short(*)[64])(lds + 128 * 64);
    const int i0 = blockIdx.x * 128, n0 = blockIdx.y * 128;
    const int tid = threadIdx.x, lane = tid & 63, w = tid >> 6;
    const int wrow = w >> 1, wcol = w & 1, g = lane >> 4, qi = lane & 15;

    f32x4 acc[4][4];
#pragma unroll
    for (int mt = 0; mt < 4; ++mt)
#pragma unroll
        for (int nt = 0; nt < 4; ++nt) acc[mt][nt] = f32x4{0.f, 0.f, 0.f, 0.f};

    gemm128_core(attn, WoT, i0, n0, A_lds, B_lds, acc);

#pragma unroll
    for (int mt = 0; mt < 4; ++mt)
#pragma unroll
        for (int nt = 0; nt < 4; ++nt) {
            int ncol = n0 + wcol * 64 + nt * 16 + qi;
            float bb = bo[ncol];
#pragma unroll
            for (int r = 0; r < 4; ++r) {
                int i = i0 + wrow * 64 + mt * 16 + 4 * g + r;
                out[(size_t)i * DMODEL + ncol] = acc[mt][nt][r] + bb;
            }
        }
}

// ---------------------------------------------------------------------------
extern "C" void kernel_launch(void* const* d_in, const int* in_sizes, int n_in,
                              void* d_out, int out_size, void* d_ws, size_t ws_size,
                              hipStream_t stream) {
    const float* Q  = (const float*)d_in[0];
    const float* K  = (const float*)d_in[1];
    const float* V  = (const float*)d_in[2];
    const float* Wq = (const float*)d_in[3];
    const float* bq = (const float*)d_in[4];
    const float* Wk = (const float*)d_in[5];
    const float* bk = (const float*)d_in[6];
    const float* Wv = (const float*)d_in[7];
    const float* bv = (const float*)d_in[8];
    const float* Wo = (const float*)d_in[9];
    const float* bo = (const float*)d_in[10];

    // ws layout (shorts): WT[4M] | q[4M] | k[4M] | vT[4M] | xb[12M]
    // attn output reuses the xb region (xb consumed by qkv_gemm before attn runs)
    const size_t WSZ = (size_t)DMODEL * DMODEL;      // 1M
    const size_t XSZ = (size_t)NB * SEQ * DMODEL;    // 4M
    if (ws_size < (4 * WSZ + 6 * XSZ) * sizeof(short)) return;  // 56 MB

    short* WT      = (short*)d_ws;
    short* q_ws    = WT + 4 * WSZ;
    short* k_ws    = q_ws + XSZ;
    short* vT_ws   = k_ws + XSZ;
    short* xb      = vT_ws + XSZ;
    short* attn_ws = xb;  // reuse

    prep_kernel<<<dim3(12288 + 4096), 256, 0, stream>>>(
        Q, K, V, Wq, Wk, Wv, Wo, xb, WT);
    qkv_gemm_kernel<<<dim3((NB * SEQ) / 128, DMODEL / 128, 3), 256, 0, stream>>>(
        xb, WT, bq, bk, bv, q_ws, k_ws, vT_ws);
    attn_kernel<<<dim3(SEQ / 64, NB * NH), 256, 0, stream>>>(
        q_ws, k_ws, vT_ws, attn_ws);
    oproj_kernel<<<dim3((NB * SEQ) / 128, DMODEL / 128), 256, 0, stream>>>(
        attn_ws, WT + 3 * WSZ, bo, (float*)d_out);
}

// Round 4
// 260.993 us; speedup vs baseline: 1.0488x; 1.0488x over previous
//
#include <hip/hip_runtime.h>
#include <hip/hip_bf16.h>

#define DMODEL 1024
#define SEQ    2048
#define NB     2
#define NH     16
#define DKH    64

typedef __attribute__((ext_vector_type(4))) float  f32x4;
typedef __attribute__((ext_vector_type(8))) __bf16 bf16x8;
typedef __attribute__((ext_vector_type(8))) short  short8;
typedef __attribute__((ext_vector_type(4))) short  short4v;

__device__ __forceinline__ short f2bf(float f) {
    __bf16 b = (__bf16)f;
    return __builtin_bit_cast(short, b);
}

__device__ __forceinline__ f32x4 mfma16(short8 a, short8 b, f32x4 c) {
    return __builtin_amdgcn_mfma_f32_16x16x32_bf16(
        __builtin_bit_cast(bf16x8, a), __builtin_bit_cast(bf16x8, b), c, 0, 0, 0);
}

// async global->LDS, 16B per lane (dest = wave-uniform base + lane*16)
__device__ __forceinline__ void async16(const void* gptr, void* lptr) {
    __builtin_amdgcn_global_load_lds(
        (const __attribute__((address_space(1))) void*)gptr,
        (__attribute__((address_space(3))) void*)lptr, 16, 0, 0);
}

// ---------------------------------------------------------------------------
// Prep (fused): bid<12288 -> Q/K/V fp32->bf16; else -> W transpose+cast.
// ---------------------------------------------------------------------------
__global__ __launch_bounds__(256) void prep_kernel(
    const float* __restrict__ Q, const float* __restrict__ K,
    const float* __restrict__ V,
    const float* __restrict__ W0, const float* __restrict__ W1,
    const float* __restrict__ W2, const float* __restrict__ W3,
    short* __restrict__ xb, short* __restrict__ WT) {
    __shared__ float tile[32][33];
    const int bid = blockIdx.x;
    if (bid < 12288) {
        const int z = bid >> 12;
        const float* src = (z == 0) ? Q : (z == 1) ? K : V;
        size_t i = (size_t)(bid & 4095) * 256 + threadIdx.x;  // float4 idx, 1M/input
        float4 v = ((const float4*)src)[i];
        short4v s;
        s[0] = f2bf(v.x); s[1] = f2bf(v.y); s[2] = f2bf(v.z); s[3] = f2bf(v.w);
        ((short4v*)(xb + (size_t)z * (NB * SEQ) * DMODEL))[i] = s;
    } else {
        const int t = bid - 12288;
        const int z = t >> 10, tt = t & 1023;
        const float* W = (z == 0) ? W0 : (z == 1) ? W1 : (z == 2) ? W2 : W3;
        short* o = WT + (size_t)z * DMODEL * DMODEL;
        const int k0 = (tt & 31) * 32, n0 = (tt >> 5) * 32;
        const int c = threadIdx.x & 31, r8 = threadIdx.x >> 5;
#pragma unroll
        for (int rr = 0; rr < 4; ++rr) {
            int row = r8 + 8 * rr;
            tile[row][c] = W[(size_t)(k0 + row) * DMODEL + n0 + c];
        }
        __syncthreads();
#pragma unroll
        for (int rr = 0; rr < 4; ++rr) {
            int n = r8 + 8 * rr;
            o[(size_t)(n0 + n) * DMODEL + k0 + c] = f2bf(tile[c][n]);
        }
    }
}

// ---------------------------------------------------------------------------
// m97-style NT GEMM core: 128x128 tile, BK=64, global_load_lds(16B) staging,
// 4 waves (2x2), each wave 64x64 out = 4x4 fragments of 16x16x32.
// ---------------------------------------------------------------------------
__device__ __forceinline__ void gemm128_core(
    const short* __restrict__ A, const short* __restrict__ BT,
    int i0, int n0, short (*A_lds)[64], short (*B_lds)[64], f32x4 acc[4][4]) {
    const int tid = threadIdx.x, lane = tid & 63, w = tid >> 6;
    const int wrow = w >> 1, wcol = w & 1, g = lane >> 4, qi = lane & 15;
    const int srow = lane >> 3, scol = (lane & 7) * 8;  // staging: lane covers 16B

    for (int k0 = 0; k0 < DMODEL; k0 += 64) {
#pragma unroll
        for (int i = 0; i < 4; ++i) {
            int t = w * 4 + i;  // 1KB chunk = 8 rows of 64 bf16
            async16(A  + (size_t)(i0 + 8 * t + srow) * DMODEL + k0 + scol, &A_lds[8 * t][0]);
            async16(BT + (size_t)(n0 + 8 * t + srow) * DMODEL + k0 + scol, &B_lds[8 * t][0]);
        }
        __syncthreads();
#pragma unroll
        for (int kc = 0; kc < 2; ++kc) {
            short8 a[4], b[4];
#pragma unroll
            for (int mt = 0; mt < 4; ++mt)
                a[mt] = *(const short8*)&A_lds[wrow * 64 + mt * 16 + qi][kc * 32 + g * 8];
#pragma unroll
            for (int nt = 0; nt < 4; ++nt)
                b[nt] = *(const short8*)&B_lds[wcol * 64 + nt * 16 + qi][kc * 32 + g * 8];
#pragma unroll
            for (int mt = 0; mt < 4; ++mt)
#pragma unroll
                for (int nt = 0; nt < 4; ++nt)
                    acc[mt][nt] = mfma16(a[mt], b[nt], acc[mt][nt]);
        }
        __syncthreads();
    }
}

// ---------------------------------------------------------------------------
// QKV projection: z=0 q (scaled by log2e/sqrt(dk)), z=1 k -> [B,H,S,Dk];
// z=2 v -> [B,H,Dk,S]
// ---------------------------------------------------------------------------
__global__ __launch_bounds__(256) void qkv_gemm_kernel(
    const short* __restrict__ xb, const short* __restrict__ WT,
    const float* __restrict__ bq, const float* __restrict__ bk,
    const float* __restrict__ bv,
    short* __restrict__ q_out, short* __restrict__ k_out, short* __restrict__ vT_out) {
    __shared__ __align__(16) short lds[128 * 128];
    short (*A_lds)[64]  = (short(*)[64])lds;
    short (*B_lds)[64]  = (short(*)[64])(lds + 128 * 64);
    short (*C_lds)[128] = (short(*)[128])lds;

    const int z = blockIdx.z;
    const short* A  = xb + (size_t)z * (NB * SEQ) * DMODEL;
    const short* BT = WT + (size_t)z * DMODEL * DMODEL;
    const float* bias = (z == 0) ? bq : (z == 1) ? bk : bv;
    // fold 1/sqrt(64) * log2(e) into q so attn softmax runs in exp2 domain
    const float scale = (z == 0) ? 0.125f * 1.44269504f : 1.0f;
    const int i0 = blockIdx.x * 128, n0 = blockIdx.y * 128;
    const int tid = threadIdx.x, lane = tid & 63, w = tid >> 6;
    const int wrow = w >> 1, wcol = w & 1, g = lane >> 4, qi = lane & 15;

    f32x4 acc[4][4];
#pragma unroll
    for (int mt = 0; mt < 4; ++mt)
#pragma unroll
        for (int nt = 0; nt < 4; ++nt) acc[mt][nt] = f32x4{0.f, 0.f, 0.f, 0.f};

    gemm128_core(A, BT, i0, n0, A_lds, B_lds, acc);

    // epilogue: bias+scale -> bf16 -> LDS repack ([i][n] for q/k, [n][i] for v)
#pragma unroll
    for (int mt = 0; mt < 4; ++mt)
#pragma unroll
        for (int nt = 0; nt < 4; ++nt) {
            int nl = wcol * 64 + nt * 16 + qi;
            float bb = bias[n0 + nl];
#pragma unroll
            for (int r = 0; r < 4; ++r) {
                int il = wrow * 64 + mt * 16 + 4 * g + r;
                short v = f2bf((acc[mt][nt][r] + bb) * scale);
                if (z == 2) C_lds[nl][il] = v;
                else        C_lds[il][nl] = v;
            }
        }
    __syncthreads();
    const int b = i0 >> 11, s0 = i0 & 2047;
#pragma unroll
    for (int rr = 0; rr < 8; ++rr) {
        int c = tid + 256 * rr;              // 2048 chunks of 8 shorts
        int row = c >> 4, off = (c & 15) * 8;
        short8 v8 = *(const short8*)&C_lds[row][off];
        if (z == 2) {  // row = n-local (head,d), off over s
            int h = (n0 + row) >> 6, d = (n0 + row) & 63;
            *(short8*)(vT_out + ((size_t)(b * NH + h) * DKH + d) * SEQ + s0 + off) = v8;
        } else {       // row = s-local, off over n (head,d)
            int h = (n0 + off) >> 6, d = (n0 + off) & 63;
            short* outp = (z == 0) ? q_out : k_out;
            *(short8*)(outp + ((size_t)(b * NH + h) * SEQ + (s0 + row)) * DKH + d) = v8;
        }
    }
}

// ---------------------------------------------------------------------------
// Flash attention: grid (S/64, B*H), 4 waves x 16 queries, KVBLK=64.
// Double-buffered K/V, XOR-swizzled LDS, exp2-domain softmax, defer-max,
// l accumulated via MFMA ones-column (no psum VALU), setprio on MFMA clusters.
// ---------------------------------------------------------------------------
__global__ __launch_bounds__(256) void attn_kernel(
    const short* __restrict__ q_ws, const short* __restrict__ k_ws,
    const short* __restrict__ vT_ws, short* __restrict__ attn_out) {
    __shared__ __align__(16) short K_lds[2][64][64];
    __shared__ __align__(16) short V_lds[2][64][64];   // vT tile: [d][j]
    __shared__ __align__(16) short P_lds[4][16][64];   // per-wave
    const int bh = blockIdx.y, q0 = blockIdx.x * 64;
    const short* qg = q_ws + (size_t)bh * SEQ * DKH;
    const short* kg = k_ws + (size_t)bh * SEQ * DKH;
    const short* vg = vT_ws + (size_t)bh * DKH * SEQ;
    const int tid = threadIdx.x, lane = tid & 63, w = tid >> 6;
    const int g = lane >> 4, qi = lane & 15;
    const int swz = (qi & 7) << 3;  // XOR on short-index == byte ^ ((row&7)<<4)

    // Q fragments (B operand), rows q0 + w*16 + qi — live whole kernel
    short8 qf[2];
#pragma unroll
    for (int c = 0; c < 2; ++c)
        qf[c] = *(const short8*)(qg + (size_t)(q0 + w * 16 + qi) * DKH + c * 32 + g * 8);

    short8 ones;
#pragma unroll
    for (int e = 0; e < 8; ++e) ones[e] = (short)0x3F80;  // bf16 1.0

    // staging registers (T14 issue-early / write-late)
    const int srow = tid >> 3;
    const int soff = (tid & 7) * 8;
    short8 kr[2], vr[2];
    auto LOADT = [&](int it) {
        const short* kbase = kg + (size_t)it * 64 * DKH;
        const short* vbase = vg + it * 64;
#pragma unroll
        for (int rr = 0; rr < 2; ++rr) {
            int row = srow + 32 * rr;
            kr[rr] = *(const short8*)(kbase + (size_t)row * DKH + soff);
            vr[rr] = *(const short8*)(vbase + (size_t)row * SEQ + soff);
        }
    };
    auto STORET = [&](int buf) {
#pragma unroll
        for (int rr = 0; rr < 2; ++rr) {
            int row = srow + 32 * rr;
            int so = soff ^ ((row & 7) << 3);
            *(short8*)&K_lds[buf][row][so] = kr[rr];
            *(short8*)&V_lds[buf][row][so] = vr[rr];
        }
    };

    LOADT(0);
    STORET(0);

    f32x4 o[4];
#pragma unroll
    for (int dt = 0; dt < 4; ++dt) o[dt] = f32x4{0.f, 0.f, 0.f, 0.f};
    f32x4 l_acc = f32x4{0.f, 0.f, 0.f, 0.f};  // rowsum via MFMA; rows = query 4g+r
    float m_run = -1e30f;
    const int NT = SEQ / 64;

    for (int it = 0; it < NT; ++it) {
        const int cur = it & 1;
        __syncthreads();  // buf[cur] staged for all; buf[cur^1] free to overwrite
        if (it + 1 < NT) LOADT(it + 1);  // issue next-tile global loads early

        // S^T = K * Q^T : lane holds 16 scores for query qi, keys jt*16+4*g+r
        f32x4 st[4];
#pragma unroll
        for (int jt = 0; jt < 4; ++jt) st[jt] = f32x4{0.f, 0.f, 0.f, 0.f};
        __builtin_amdgcn_s_setprio(1);
#pragma unroll
        for (int jt = 0; jt < 4; ++jt)
#pragma unroll
            for (int c = 0; c < 2; ++c) {
                short8 a = *(const short8*)&K_lds[cur][jt * 16 + qi][(c * 32 + g * 8) ^ swz];
                st[jt] = mfma16(a, qf[c], st[jt]);
            }
        __builtin_amdgcn_s_setprio(0);

        float sv[16];
#pragma unroll
        for (int jt = 0; jt < 4; ++jt)
#pragma unroll
            for (int r = 0; r < 4; ++r) sv[jt * 4 + r] = st[jt][r];  // log2 domain

        // max via v_max3-friendly tree (15 fmax -> ~8 instrs)
        float pmax = fmaxf(fmaxf(sv[0], sv[1]), sv[2]);
        pmax = fmaxf(fmaxf(pmax, sv[3]), sv[4]);
        pmax = fmaxf(fmaxf(pmax, sv[5]), sv[6]);
        pmax = fmaxf(fmaxf(pmax, sv[7]), sv[8]);
        pmax = fmaxf(fmaxf(pmax, sv[9]), sv[10]);
        pmax = fmaxf(fmaxf(pmax, sv[11]), sv[12]);
        pmax = fmaxf(fmaxf(pmax, sv[13]), sv[14]);
        pmax = fmaxf(pmax, sv[15]);
        pmax = fmaxf(pmax, __shfl_xor(pmax, 16));
        pmax = fmaxf(pmax, __shfl_xor(pmax, 32));

        // defer-max (T13): threshold 8*log2e in exp2 domain
        float m_new = m_run, fct = 1.0f;
        const int need = !__all(pmax <= m_run + 11.54f);
        if (need) { m_new = fmaxf(m_run, pmax); fct = exp2f(m_run - m_new); }

#pragma unroll
        for (int i = 0; i < 16; ++i) sv[i] = exp2f(sv[i] - m_new);  // bare v_exp_f32
        m_run = m_new;

        // P (bf16) to per-wave LDS: row = query qi, col = key (swizzled)
#pragma unroll
        for (int jt = 0; jt < 4; ++jt) {
            short4v pk;
#pragma unroll
            for (int r = 0; r < 4; ++r) pk[r] = f2bf(sv[jt * 4 + r]);
            *(short4v*)&P_lds[w][qi][(jt * 16 + 4 * g) ^ swz] = pk;
        }

        if (need) {  // rescale O and l rows (query 4*g+r)
            float fr[4];
#pragma unroll
            for (int r = 0; r < 4; ++r) fr[r] = __shfl(fct, 4 * g + r);
#pragma unroll
            for (int dt = 0; dt < 4; ++dt)
#pragma unroll
                for (int r = 0; r < 4; ++r) o[dt][r] *= fr[r];
#pragma unroll
            for (int r = 0; r < 4; ++r) l_acc[r] *= fr[r];
        }

        if (it + 1 < NT) STORET(cur ^ 1);  // write-late into the free buffer

        // O += P * V ; l += P * 1 (rowsum via same A fragments)
        __builtin_amdgcn_s_setprio(1);
#pragma unroll
        for (int c = 0; c < 2; ++c) {
            short8 ap = *(const short8*)&P_lds[w][qi][(c * 32 + g * 8) ^ swz];
            l_acc = mfma16(ap, ones, l_acc);
#pragma unroll
            for (int dt = 0; dt < 4; ++dt) {
                short8 bvv = *(const short8*)&V_lds[cur][dt * 16 + qi][(c * 32 + g * 8) ^ swz];
                o[dt] = mfma16(ap, bvv, o[dt]);
            }
        }
        __builtin_amdgcn_s_setprio(0);
    }

    const int b = bh >> 4, h = bh & 15;
    float lr[4];
#pragma unroll
    for (int r = 0; r < 4; ++r) lr[r] = 1.0f / l_acc[r];
#pragma unroll
    for (int dt = 0; dt < 4; ++dt)
#pragma unroll
        for (int r = 0; r < 4; ++r) {
            int spos = q0 + w * 16 + 4 * g + r;
            attn_out[(size_t)(b * SEQ + spos) * DMODEL + h * 64 + dt * 16 + qi] =
                f2bf(o[dt][r] * lr[r]);
        }
}

// ---------------------------------------------------------------------------
// Output projection: 128x64 tile (512 blocks -> 2/CU), bf16 NT GEMM -> fp32+bias
// 4 waves stacked on M; per-wave 32x64 out = 2x4 fragments.
// ---------------------------------------------------------------------------
__global__ __launch_bounds__(256) void oproj_kernel(
    const short* __restrict__ attn, const short* __restrict__ WoT,
    const float* __restrict__ bo, float* __restrict__ out) {
    __shared__ __align__(16) short A_lds[128][64];  // 16 KB
    __shared__ __align__(16) short B_lds[64][64];   // 8 KB
    const int i0 = blockIdx.x * 128, n0 = blockIdx.y * 64;
    const int tid = threadIdx.x, lane = tid & 63, w = tid >> 6;
    const int g = lane >> 4, qi = lane & 15;
    const int srow = lane >> 3, scol = (lane & 7) * 8;

    f32x4 acc[2][4];
#pragma unroll
    for (int mt = 0; mt < 2; ++mt)
#pragma unroll
        for (int nt = 0; nt < 4; ++nt) acc[mt][nt] = f32x4{0.f, 0.f, 0.f, 0.f};

    for (int k0 = 0; k0 < DMODEL; k0 += 64) {
#pragma unroll
        for (int i = 0; i < 4; ++i) {
            int t = w * 4 + i;  // A: 16 chunks of 8 rows
            async16(attn + (size_t)(i0 + 8 * t + srow) * DMODEL + k0 + scol, &A_lds[8 * t][0]);
        }
#pragma unroll
        for (int i = 0; i < 2; ++i) {
            int t = w * 2 + i;  // B: 8 chunks of 8 rows
            async16(WoT + (size_t)(n0 + 8 * t + srow) * DMODEL + k0 + scol, &B_lds[8 * t][0]);
        }
        __syncthreads();
#pragma unroll
        for (int kc = 0; kc < 2; ++kc) {
            short8 a[2], b[4];
#pragma unroll
            for (int mt = 0; mt < 2; ++mt)
                a[mt] = *(const short8*)&A_lds[w * 32 + mt * 16 + qi][kc * 32 + g * 8];
#pragma unroll
            for (int nt = 0; nt < 4; ++nt)
                b[nt] = *(const short8*)&B_lds[nt * 16 + qi][kc * 32 + g * 8];
#pragma unroll
            for (int mt = 0; mt < 2; ++mt)
#pragma unroll
                for (int nt = 0; nt < 4; ++nt)
                    acc[mt][nt] = mfma16(a[mt], b[nt], acc[mt][nt]);
        }
        __syncthreads();
    }

#pragma unroll
    for (int mt = 0; mt < 2; ++mt)
#pragma unroll
        for (int nt = 0; nt < 4; ++nt) {
            int ncol = n0 + nt * 16 + qi;
            float bb = bo[ncol];
#pragma unroll
            for (int r = 0; r < 4; ++r) {
                int i = i0 + w * 32 + mt * 16 + 4 * g + r;
                out[(size_t)i * DMODEL + ncol] = acc[mt][nt][r] + bb;
            }
        }
}

// ---------------------------------------------------------------------------
extern "C" void kernel_launch(void* const* d_in, const int* in_sizes, int n_in,
                              void* d_out, int out_size, void* d_ws, size_t ws_size,
                              hipStream_t stream) {
    const float* Q  = (const float*)d_in[0];
    const float* K  = (const float*)d_in[1];
    const float* V  = (const float*)d_in[2];
    const float* Wq = (const float*)d_in[3];
    const float* bq = (const float*)d_in[4];
    const float* Wk = (const float*)d_in[5];
    const float* bk = (const float*)d_in[6];
    const float* Wv = (const float*)d_in[7];
    const float* bv = (const float*)d_in[8];
    const float* Wo = (const float*)d_in[9];
    const float* bo = (const float*)d_in[10];

    // ws layout (shorts): WT[4M] | q[4M] | k[4M] | vT[4M] | xb[12M]
    // attn output reuses the xb region (xb consumed by qkv_gemm before attn runs)
    const size_t WSZ = (size_t)DMODEL * DMODEL;      // 1M
    const size_t XSZ = (size_t)NB * SEQ * DMODEL;    // 4M
    if (ws_size < (4 * WSZ + 6 * XSZ) * sizeof(short)) return;  // 56 MB

    short* WT      = (short*)d_ws;
    short* q_ws    = WT + 4 * WSZ;
    short* k_ws    = q_ws + XSZ;
    short* vT_ws   = k_ws + XSZ;
    short* xb      = vT_ws + XSZ;
    short* attn_ws = xb;  // reuse

    prep_kernel<<<dim3(12288 + 4096), 256, 0, stream>>>(
        Q, K, V, Wq, Wk, Wv, Wo, xb, WT);
    qkv_gemm_kernel<<<dim3((NB * SEQ) / 128, DMODEL / 128, 3), 256, 0, stream>>>(
        xb, WT, bq, bk, bv, q_ws, k_ws, vT_ws);
    attn_kernel<<<dim3(SEQ / 64, NB * NH), 256, 0, stream>>>(
        q_ws, k_ws, vT_ws, attn_ws);
    oproj_kernel<<<dim3((NB * SEQ) / 128, DMODEL / 64), 256, 0, stream>>>(
        attn_ws, WT + 3 * WSZ, bo, (float*)d_out);
}